// Round 14
// baseline (328.510 us; speedup 1.0000x reference)
//
#include <hip/hip_runtime.h>
#include <hip/hip_bf16.h>
#include <stdint.h>

// ---------------------------------------------------------------------------
// SpecWaveTransformer on MI355X.
// B=2 C=8 MAPS=4 HEADS=8 F=256 W=1024 HD=32.  Outputs: out[2,8,256,1024] f32,
// qk[2,4,8,1024,1024] f32 (concatenated in d_out).
// ---------------------------------------------------------------------------

typedef __attribute__((ext_vector_type(8))) short s16x8;
typedef __attribute__((ext_vector_type(4))) float f32x4;

#define MFMA16(a, b, c) __builtin_amdgcn_mfma_f32_16x16x32_bf16((a), (b), (c), 0, 0, 0)

__device__ __forceinline__ short f2bf(float f) {
  unsigned u = __builtin_bit_cast(unsigned, f);
  u = (u + 0x7FFFu + ((u >> 16) & 1u)) >> 16;
  return (short)u;
}
__device__ __forceinline__ unsigned pack2(float a, float b) {
  return (unsigned)(unsigned short)f2bf(a) | ((unsigned)(unsigned short)f2bf(b) << 16);
}
__device__ __forceinline__ float bf2f(unsigned u) {
  return __builtin_bit_cast(float, u << 16);
}

// ---------------------------------------------------------------------------
// K0: prep — bf16 casts of linear weights + RoPE cos/sin table [1024][16]
// ---------------------------------------------------------------------------
__global__ __launch_bounds__(256) void k_prep(const float* wq, const float* wk,
                                              const float* wv, const float* wo,
                                              short* wlin, short* wob, float* ct, float* st) {
  int i = blockIdx.x * 256 + threadIdx.x;
  if (i < 262144) wlin[i] = f2bf(wq[i]);
  else if (i < 524288) wlin[i] = f2bf(wk[i - 262144]);
  else if (i < 786432) wlin[i] = f2bf(wv[i - 524288]);
  if (i < 786432) wob[i] = f2bf(wo[i]);
  if (i < 16384) {
    int w = i >> 4, j = i & 15;
    float inv = exp2f(-(float)j * (13.287712379549449f / 16.0f));
    float ang = (float)w * inv;
    ct[i] = cosf(ang);
    st[i] = sinf(ang);
  }
}

// ---------------------------------------------------------------------------
// K1: conv3x3 SAME over (F,W); block = (m, b, f-strip of 4), computes ALL 3 p
// ---------------------------------------------------------------------------
__device__ __forceinline__ void loadrow(float* r, const float* xc, int f, int w0) {
  if (f < 0 || f > 255) {
#pragma unroll
    for (int jj = 0; jj < 6; ++jj) r[jj] = 0.f;
    return;
  }
  const float* row = xc + f * 1024;
#pragma unroll
  for (int jj = 0; jj < 6; ++jj) {
    int wc = w0 - 1 + jj;
    r[jj] = (wc >= 0 && wc < 1024) ? row[wc] : 0.f;
  }
}

__global__ __launch_bounds__(256) void k_conv(const float* x, const float* wqc, const float* bq,
                                              const float* wkc, const float* bk,
                                              const float* wvc, const float* bv, short* y) {
  int blk = blockIdx.x;  // 512 = 4 m * 2 b * 64 fstrips
  int m_ = blk >> 7;
  int b_ = (blk >> 6) & 1;
  int fs = blk & 63;
  int f0 = fs * 4;
  int w0 = threadIdx.x * 4;
  const float* xb = x + (size_t)b_ * 2097152;
  const float* wp_[3] = {wqc + m_ * 72, wkc + m_ * 72, wvc + m_ * 72};
  float bias_[3] = {bq[m_], bk[m_], bv[m_]};

  float acc[3][4][4];
#pragma unroll
  for (int p = 0; p < 3; ++p)
#pragma unroll
    for (int fi = 0; fi < 4; ++fi)
#pragma unroll
      for (int j = 0; j < 4; ++j) acc[p][fi][j] = bias_[p];

  for (int c = 0; c < 8; ++c) {
    const float* xc = xb + c * 262144;
    float w9[3][9];
#pragma unroll
    for (int p = 0; p < 3; ++p)
#pragma unroll
      for (int t = 0; t < 9; ++t) w9[p][t] = wp_[p][c * 9 + t];
    float rows[6][6];
#pragma unroll
    for (int ri = 0; ri < 6; ++ri) loadrow(rows[ri], xc, f0 - 1 + ri, w0);
#pragma unroll
    for (int fi = 0; fi < 4; ++fi) {
#pragma unroll
      for (int p = 0; p < 3; ++p) {
#pragma unroll
        for (int j = 0; j < 4; ++j) {
          float s = acc[p][fi][j];
          s += rows[fi][j] * w9[p][0] + rows[fi][j + 1] * w9[p][1] + rows[fi][j + 2] * w9[p][2];
          s += rows[fi + 1][j] * w9[p][3] + rows[fi + 1][j + 1] * w9[p][4] + rows[fi + 1][j + 2] * w9[p][5];
          s += rows[fi + 2][j] * w9[p][6] + rows[fi + 2][j + 1] * w9[p][7] + rows[fi + 2][j + 2] * w9[p][8];
          acc[p][fi][j] = s;
        }
      }
    }
  }
#pragma unroll
  for (int p = 0; p < 3; ++p) {
    int mat = p * 8 + b_ * 4 + m_;
    short* yp = y + (size_t)mat * 262144;
#pragma unroll
    for (int fi = 0; fi < 4; ++fi) {
      uint2 pk;
      pk.x = pack2(acc[p][fi][0], acc[p][fi][1]);
      pk.y = pack2(acc[p][fi][2], acc[p][fi][3]);
      *(uint2*)(yp + (f0 + fi) * 1024 + w0) = pk;
    }
  }
}

// ---------------------------------------------------------------------------
// K3: per-map linear (MFMA GEMM) + RoPE, with FUSED y-transpose.
// ---------------------------------------------------------------------------
__global__ __launch_bounds__(256) void k_qkv(const short* wlin, const short* y,
                                             const float* ct, const float* st,
                                             short* qws, short* kws, short* vws) {
  __shared__ short ytile[64][264];
  int blk = blockIdx.x;  // 24 pbm * 16 wtiles
  int pbm = blk >> 4, wt = blk & 15;
  int p = pbm >> 3, bm = pbm & 7;
  int m_ = bm & 3;
  int tid = threadIdx.x, wv = tid >> 6, l = tid & 63, lr = l & 15, lg = l >> 4;
  const short* wl = wlin + (p * 4 + m_) * 65536;
  const short* yp = y + (size_t)pbm * 262144;
  int w0 = wt * 64;
  int G0 = wv * 64;

  // ---- stage + transpose: wave wv covers f rows [wv*64, wv*64+64) ----
  {
    int h2 = l >> 5, lih = l & 31;
#pragma unroll
    for (int i = 0; i < 32; ++i) {
      int f = wv * 64 + i * 2 + h2;
      unsigned u = *(const unsigned*)(yp + f * 1024 + w0 + lih * 2);
      ytile[lih * 2][f] = (short)(u & 0xffffu);
      ytile[lih * 2 + 1][f] = (short)(u >> 16);
    }
  }
  __syncthreads();

  f32x4 acc[4][4];
#pragma unroll
  for (int i = 0; i < 4; ++i)
#pragma unroll
    for (int j = 0; j < 4; ++j) acc[i][j] = (f32x4){0.f, 0.f, 0.f, 0.f};

  if (p < 2) {
    for (int kc = 0; kc < 256; kc += 32) {
      s16x8 A[4], Bf[4];
#pragma unroll
      for (int gs = 0; gs < 4; ++gs)
        A[gs] = *(const s16x8*)(wl + (G0 + gs * 16 + lr) * 256 + kc + lg * 8);
#pragma unroll
      for (int s = 0; s < 4; ++s)
        Bf[s] = *(const s16x8*)(&ytile[s * 16 + lr][kc + lg * 8]);
#pragma unroll
      for (int gs = 0; gs < 4; ++gs)
#pragma unroll
        for (int s = 0; s < 4; ++s) acc[gs][s] = MFMA16(A[gs], Bf[s], acc[gs][s]);
    }
    short* dst = (p == 0) ? qws : kws;
    float scale = (p == 0) ? 0.0625f : 1.0f;  // fold 1/sqrt(256) into Q
#pragma unroll
    for (int gs = 0; gs < 4; ++gs) {
      int g0v = G0 + gs * 16 + lg * 4;
      int h = g0v >> 5, d0 = g0v & 31;
      int i0 = d0 >> 1;
#pragma unroll
      for (int s = 0; s < 4; ++s) {
        int w = w0 + s * 16 + lr;
        float c0 = ct[w * 16 + i0], sn0 = st[w * 16 + i0];
        float c1 = ct[w * 16 + i0 + 1], sn1 = st[w * 16 + i0 + 1];
        f32x4 v = acc[gs][s];
        float e0 = (v[0] * c0 - v[1] * sn0) * scale;
        float e1 = (v[1] * c0 + v[0] * sn0) * scale;
        float e2 = (v[2] * c1 - v[3] * sn1) * scale;
        float e3 = (v[3] * c1 + v[2] * sn1) * scale;
        uint2 pk;
        pk.x = pack2(e0, e1);
        pk.y = pack2(e2, e3);
        *(uint2*)(dst + (((size_t)bm * 8 + h) * 1024 + w) * 32 + d0) = pk;
      }
    }
  } else {
    for (int kc = 0; kc < 256; kc += 32) {
      s16x8 A[4], Bf[4];
#pragma unroll
      for (int s = 0; s < 4; ++s)
        A[s] = *(const s16x8*)(&ytile[s * 16 + lr][kc + lg * 8]);
#pragma unroll
      for (int gs = 0; gs < 4; ++gs)
        Bf[gs] = *(const s16x8*)(wl + (G0 + gs * 16 + lr) * 256 + kc + lg * 8);
#pragma unroll
      for (int s = 0; s < 4; ++s)
#pragma unroll
        for (int gs = 0; gs < 4; ++gs) acc[s][gs] = MFMA16(A[s], Bf[gs], acc[s][gs]);
    }
#pragma unroll
    for (int s = 0; s < 4; ++s) {
      int wb = w0 + s * 16 + lg * 4;
#pragma unroll
      for (int gs = 0; gs < 4; ++gs) {
        int g = G0 + gs * 16 + lr;
        f32x4 v = acc[s][gs];
        uint2 pk;
        pk.x = pack2(v[0], v[1]);
        pk.y = pack2(v[2], v[3]);
        *(uint2*)(vws + ((size_t)bm * 256 + g) * 1024 + wb) = pk;
      }
    }
  }
}

// ---------------------------------------------------------------------------
// K4: fused attention (R9 structure, prev prefetch deepened 2 -> 4 windows:
// in-flight/wave 8KB -> 16KB; VGPR +32 is free, occupancy is LDS-capped).
// K+V staged to LDS once per block; steady-state vmem = prev read stream +
// qk store stream.  4 waves/block, 1 block/CU, zero in-loop barriers.
// ---------------------------------------------------------------------------
__global__ __launch_bounds__(256, 1) void k_attn(const short* qws, const short* kws,
                                                 const short* vws, const float* prev,
                                                 float* qko, short* aT) {
  __shared__ char smem[155648];
  // LDS: K [0,64K): row k(1024) x 64B, xor ((k&3)<<4)
  //      V [64K,128K): row g(32) x 2048B, xor ((g&7)<<4)
  //      S [128K + wv*4K): 16 q x 256B, xor ((q&7)<<4)
  //      P [144K + wv*2K): 16 q x 128B, xor ((q&7)<<4)
  int blk = blockIdx.x;  // 1024 = 64 bmh * 16 qg
  int bmh = blk >> 4;
  int qg = blk & 15;
  int h = bmh & 7, bm = bmh >> 3;
  int tid = threadIdx.x;
  int wv = tid >> 6, l = tid & 63, lr = l & 15, lg = l >> 4;
  const short* kp = kws + (size_t)bmh * 32768;
  const short* vp = vws + ((size_t)bm * 256 + h * 32) * 1024;

  // ---- stage K (64KB): 16 iters, 64 rows x 64B each (256 thr x 16B) ----
  {
    int row4 = tid >> 2, c = tid & 3;
#pragma unroll
    for (int i = 0; i < 16; ++i) {
      int row = i * 64 + row4;
      s16x8 kv = *(const s16x8*)(kp + row * 32 + c * 8);
      *(s16x8*)(smem + row * 64 + ((c * 16) ^ ((row & 3) << 4))) = kv;
    }
    // ---- stage V (64KB): 16 iters, 2 rows x 2048B each ----
    int g2 = tid >> 7, cb = (tid & 127) * 16;
#pragma unroll
    for (int i = 0; i < 16; ++i) {
      int g = i * 2 + g2;
      s16x8 vv = *(const s16x8*)(vp + g * 1024 + (cb >> 1));
      *(s16x8*)(smem + 65536 + g * 2048 + (cb ^ ((g & 7) << 4))) = vv;
    }
  }
  __syncthreads();

  int q0 = qg * 64 + wv * 16;
  const short* qp = qws + (size_t)bmh * 32768;
  s16x8 qf = *(const s16x8*)(qp + (q0 + lr) * 32 + lg * 8);
  char* Sb = smem + 131072 + wv * 4096;
  char* Pb = smem + 147456 + wv * 2048;
  const float* pvb = prev + (size_t)bmh * 1048576 + (size_t)q0 * 1024;
  float* qob = qko + (size_t)bmh * 1048576 + (size_t)q0 * 1024;
  int pcol = (l & 15) * 4;   // float col within window
  int pcolb = pcol * 4;      // byte col within S row
  f32x4 o0 = {0.f, 0.f, 0.f, 0.f}, o1 = {0.f, 0.f, 0.f, 0.f};
  f32x4 rs = {0.f, 0.f, 0.f, 0.f};  // rs[j]: rowsum partial for q-row j*4+lg
  const f32x4 z4 = {0.f, 0.f, 0.f, 0.f};

  // window body: consume pr (window w), refill pr with window w+4
  auto attn_win = [&](int w, f32x4(&pr)[4]) {
    int k0 = w * 64;
    // QK^T from LDS K
#pragma unroll
    for (int s = 0; s < 4; ++s) {
      int krow = k0 + s * 16 + lr;
      s16x8 kf = *(const s16x8*)(smem + krow * 64 + ((lg * 16) ^ ((krow & 3) << 4)));
      f32x4 sx = MFMA16(kf, qf, z4);  // lane: q=lr(col), k=k0+s*16+lg*4+reg
      *(f32x4*)(Sb + lr * 256 + ((s * 64 + lg * 16) ^ ((lr & 7) << 4))) = sx;
    }
    // row-IO: instr j covers q-rows j*4..j*4+3 (lane: row j*4+lg, 16B of cols)
#pragma unroll
    for (int j = 0; j < 4; ++j) {
      int qr = j * 4 + lg;
      f32x4 sv = *(const f32x4*)(Sb + qr * 256 + (pcolb ^ ((qr & 7) << 4)));
      f32x4 v = sv + pr[j];
      *(f32x4*)(qob + (size_t)qr * 1024 + k0 + pcol) = v;
      float e0 = __expf(v[0]), e1 = __expf(v[1]);
      float e2 = __expf(v[2]), e3 = __expf(v[3]);
      rs[j] += (e0 + e1) + (e2 + e3);
      uint2 pk;
      pk.x = pack2(e0, e1);
      pk.y = pack2(e2, e3);
      *(uint2*)(Pb + qr * 128 + (((l & 15) * 8) ^ ((qr & 7) << 4))) = pk;
    }
    // refill prefetch (4 windows ahead)
    if (w + 4 < 16) {
#pragma unroll
      for (int j = 0; j < 4; ++j)
        pr[j] = *(const f32x4*)(pvb + (size_t)(j * 4 + lg) * 1024 + (w + 4) * 64 + pcol);
    }
    // PV from LDS V
#pragma unroll
    for (int kc = 0; kc < 2; ++kc) {
      s16x8 pa = *(const s16x8*)(Pb + lr * 128 + ((kc * 64 + lg * 16) ^ ((lr & 7) << 4)));
      int kcb = (k0 + kc * 32 + lg * 8) * 2;
      s16x8 vf0 = *(const s16x8*)(smem + 65536 + lr * 2048 + (kcb ^ ((lr & 7) << 4)));
      o0 = MFMA16(pa, vf0, o0);
      s16x8 vf1 = *(const s16x8*)(smem + 65536 + (16 + lr) * 2048 + (kcb ^ ((lr & 7) << 4)));
      o1 = MFMA16(pa, vf1, o1);
    }
  };

  f32x4 pA[4], pB[4], pC[4], pD[4];
#pragma unroll
  for (int j = 0; j < 4; ++j)
    pA[j] = *(const f32x4*)(pvb + (size_t)(j * 4 + lg) * 1024 + 0 + pcol);
#pragma unroll
  for (int j = 0; j < 4; ++j)
    pB[j] = *(const f32x4*)(pvb + (size_t)(j * 4 + lg) * 1024 + 64 + pcol);
#pragma unroll
  for (int j = 0; j < 4; ++j)
    pC[j] = *(const f32x4*)(pvb + (size_t)(j * 4 + lg) * 1024 + 128 + pcol);
#pragma unroll
  for (int j = 0; j < 4; ++j)
    pD[j] = *(const f32x4*)(pvb + (size_t)(j * 4 + lg) * 1024 + 192 + pcol);

  for (int w = 0; w < 16; w += 4) {
    attn_win(w, pA);
    attn_win(w + 1, pB);
    attn_win(w + 2, pC);
    attn_win(w + 3, pD);
  }

  // rowsum reduce across the 16 lanes sharing lg
#pragma unroll
  for (int j = 0; j < 4; ++j) {
    float s = rs[j];
    s += __shfl_xor(s, 1);
    s += __shfl_xor(s, 2);
    s += __shfl_xor(s, 4);
    s += __shfl_xor(s, 8);
    rs[j] = s;
  }
  // route rowsums to PV-frag layout via wave-private S scratch
  if (lr == 0) {
#pragma unroll
    for (int j = 0; j < 4; ++j) *(float*)(Sb + (j * 4 + lg) * 4) = rs[j];
  }
  f32x4 sums = *(const f32x4*)(Sb + lg * 16);
  f32x4 inv = {1.f / sums[0], 1.f / sums[1], 1.f / sums[2], 1.f / sums[3]};
  o0 *= inv;
  o1 *= inv;
  short* ap = aT + (size_t)bm * 262144;
#pragma unroll
  for (int r = 0; r < 4; ++r) {
    int row = q0 + lg * 4 + r;
    ap[row * 256 + h * 32 + lr] = f2bf(o0[r]);
    ap[row * 256 + h * 32 + 16 + lr] = f2bf(o1[r]);
  }
}

// ---------------------------------------------------------------------------
// K5: FUSED z-projection + depthwise output (z never hits HBM).
// Block = (b, g-tile 32, w-tile 64) = 256 blocks.  Per c: A = xtile (staged
// transpose, c<8) or aT global frags (c>=8); 64w x 32g x 256f micro-GEMM;
// combine z_c into 8 per-o accumulators with wo_dw[o][c]; single f32 write.
// ---------------------------------------------------------------------------
__global__ __launch_bounds__(256) void k_out(const short* wopw, const float* x,
                                             const short* aT, const float* dw, float* out0) {
  __shared__ short xtile[64][264];
  __shared__ float wdw[96];
  int blk = blockIdx.x;  // 256 = 2 b * 8 gt * 16 wt
  int b_ = blk >> 7;
  int gt = (blk >> 4) & 7;
  int wt = blk & 15;
  int g0 = gt * 32, w0 = wt * 64;
  int tid = threadIdx.x, wv = tid >> 6, l = tid & 63, lr = l & 15, lg = l >> 4;
  if (tid < 96) wdw[tid] = dw[tid];

  f32x4 oacc[8][2];
#pragma unroll
  for (int o = 0; o < 8; ++o)
#pragma unroll
    for (int gs = 0; gs < 2; ++gs) oacc[o][gs] = (f32x4){0.f, 0.f, 0.f, 0.f};
  const f32x4 z4 = {0.f, 0.f, 0.f, 0.f};

  for (int c = 0; c < 12; ++c) {
    const short* wl = wopw + c * 65536;
    bool use_lds = (c < 8);
    const short* asrc = aT + ((size_t)b_ * 4 + (c - 8)) * 262144;
    if (use_lds) {
      __syncthreads();
      const float* xp = x + ((size_t)b_ * 8 + c) * 262144;
      int h2 = l >> 5, lih = l & 31;
#pragma unroll
      for (int i = 0; i < 32; ++i) {
        int f = wv * 64 + i * 2 + h2;
        uint2 u = *(const uint2*)(xp + f * 1024 + w0 + lih * 2);
        xtile[lih * 2][f] = f2bf(__builtin_bit_cast(float, u.x));
        xtile[lih * 2 + 1][f] = f2bf(__builtin_bit_cast(float, u.y));
      }
      __syncthreads();
    }
    f32x4 zacc0 = z4, zacc1 = z4;
    for (int kc = 0; kc < 256; kc += 32) {
      s16x8 A = use_lds ? *(const s16x8*)(&xtile[wv * 16 + lr][kc + lg * 8])
                        : *(const s16x8*)(asrc + (w0 + wv * 16 + lr) * 256 + kc + lg * 8);
      s16x8 B0 = *(const s16x8*)(wl + (g0 + lr) * 256 + kc + lg * 8);
      s16x8 B1 = *(const s16x8*)(wl + (g0 + 16 + lr) * 256 + kc + lg * 8);
      zacc0 = MFMA16(A, B0, zacc0);
      zacc1 = MFMA16(A, B1, zacc1);
    }
#pragma unroll
    for (int o = 0; o < 8; ++o) {
      float wc = wdw[o * 12 + c];
      oacc[o][0] += zacc0 * wc;
      oacc[o][1] += zacc1 * wc;
    }
  }
  // write: value oacc[o][gs] -> out[b][o][g0+gs*16+lr][w0+wv*16+lg*4 .. +3]
  float* ob = out0 + (size_t)b_ * 8 * 262144;
  int wb = w0 + wv * 16 + lg * 4;
#pragma unroll
  for (int o = 0; o < 8; ++o)
#pragma unroll
    for (int gs = 0; gs < 2; ++gs) {
      int g = g0 + gs * 16 + lr;
      *(f32x4*)(ob + (size_t)o * 262144 + g * 1024 + wb) = oacc[o][gs];
    }
}

// ---------------------------------------------------------------------------
extern "C" void kernel_launch(void* const* d_in, const int* in_sizes, int n_in,
                              void* d_out, int out_size, void* d_ws, size_t ws_size,
                              hipStream_t stream) {
  const float* x = (const float*)d_in[0];
  const float* prevqk = (const float*)d_in[1];
  const float* wq_conv = (const float*)d_in[2];
  const float* bq = (const float*)d_in[3];
  const float* wq_lin = (const float*)d_in[4];
  const float* wk_conv = (const float*)d_in[5];
  const float* bk = (const float*)d_in[6];
  const float* wk_lin = (const float*)d_in[7];
  const float* wv_conv = (const float*)d_in[8];
  const float* bv = (const float*)d_in[9];
  const float* wv_lin = (const float*)d_in[10];
  const float* wo_pw = (const float*)d_in[11];
  const float* wo_dw = (const float*)d_in[12];

  float* out0 = (float*)d_out;
  float* qkout = out0 + 4194304;  // out[2,8,256,1024] then qk[2,4,8,1024,1024]

  char* ws = (char*)d_ws;
  short* wlin_b = (short*)ws;               // 786432 bf16
  short* wopw_b = wlin_b + 786432;          // 786432 bf16
  float* ct = (float*)(ws + 3145728);       // 16384 f32
  float* st = ct + 16384;                   // 16384 f32
  short* y_b = (short*)(ws + 3276800);      // 6291456 bf16   y[p][b][m][f][w]
  short* q_b = y_b + 6291456;               // 2097152 bf16   q[b][m][h][w][d] (scaled 1/16)
  short* k_b = q_b + 2097152;               // 2097152 bf16
  short* v_b = k_b + 2097152;               // 2097152 bf16   v[b][m][g][w]
  short* aT_b = v_b + 2097152;              // 2097152 bf16   aT[b][m][w][f]

  k_prep<<<3072, 256, 0, stream>>>(wq_lin, wk_lin, wv_lin, wo_pw, wlin_b, wopw_b, ct, st);
  k_conv<<<512, 256, 0, stream>>>(x, wq_conv, bq, wk_conv, bk, wv_conv, bv, y_b);
  k_qkv<<<384, 256, 0, stream>>>(wlin_b, y_b, ct, st, q_b, k_b, v_b);
  k_attn<<<1024, 256, 0, stream>>>(q_b, k_b, v_b, prevqk, qkout, aT_b);
  k_out<<<256, 256, 0, stream>>>(wopw_b, x, aT_b, wo_dw, out0);
}

// Round 15
// 219.685 us; speedup vs baseline: 1.4954x; 1.4954x over previous
//
#include <hip/hip_runtime.h>
#include <hip/hip_bf16.h>
#include <stdint.h>

// ---------------------------------------------------------------------------
// SpecWaveTransformer on MI355X.
// B=2 C=8 MAPS=4 HEADS=8 F=256 W=1024 HD=32.  Outputs: out[2,8,256,1024] f32,
// qk[2,4,8,1024,1024] f32 (concatenated in d_out).
// R13 baseline (220.6us) with ONE change: attn prev prefetch 2 -> 4 deep.
// ---------------------------------------------------------------------------

typedef __attribute__((ext_vector_type(8))) short s16x8;
typedef __attribute__((ext_vector_type(4))) float f32x4;

#define MFMA16(a, b, c) __builtin_amdgcn_mfma_f32_16x16x32_bf16((a), (b), (c), 0, 0, 0)

__device__ __forceinline__ short f2bf(float f) {
  unsigned u = __builtin_bit_cast(unsigned, f);
  u = (u + 0x7FFFu + ((u >> 16) & 1u)) >> 16;
  return (short)u;
}
__device__ __forceinline__ unsigned pack2(float a, float b) {
  return (unsigned)(unsigned short)f2bf(a) | ((unsigned)(unsigned short)f2bf(b) << 16);
}
__device__ __forceinline__ float bf2f(unsigned u) {
  return __builtin_bit_cast(float, u << 16);
}

// ---------------------------------------------------------------------------
// K0: prep — bf16 casts of linear weights + RoPE cos/sin table [1024][16]
// ---------------------------------------------------------------------------
__global__ __launch_bounds__(256) void k_prep(const float* wq, const float* wk,
                                              const float* wv, const float* wo,
                                              short* wlin, short* wob, float* ct, float* st) {
  int i = blockIdx.x * 256 + threadIdx.x;
  if (i < 262144) wlin[i] = f2bf(wq[i]);
  else if (i < 524288) wlin[i] = f2bf(wk[i - 262144]);
  else if (i < 786432) wlin[i] = f2bf(wv[i - 524288]);
  if (i < 786432) wob[i] = f2bf(wo[i]);
  if (i < 16384) {
    int w = i >> 4, j = i & 15;
    float inv = exp2f(-(float)j * (13.287712379549449f / 16.0f));
    float ang = (float)w * inv;
    ct[i] = cosf(ang);
    st[i] = sinf(ang);
  }
}

// ---------------------------------------------------------------------------
// K1: conv3x3 SAME over (F,W); block = (m, b, f-strip of 4), computes ALL 3 p
// ---------------------------------------------------------------------------
__device__ __forceinline__ void loadrow(float* r, const float* xc, int f, int w0) {
  if (f < 0 || f > 255) {
#pragma unroll
    for (int jj = 0; jj < 6; ++jj) r[jj] = 0.f;
    return;
  }
  const float* row = xc + f * 1024;
#pragma unroll
  for (int jj = 0; jj < 6; ++jj) {
    int wc = w0 - 1 + jj;
    r[jj] = (wc >= 0 && wc < 1024) ? row[wc] : 0.f;
  }
}

__global__ __launch_bounds__(256) void k_conv(const float* x, const float* wqc, const float* bq,
                                              const float* wkc, const float* bk,
                                              const float* wvc, const float* bv, short* y) {
  int blk = blockIdx.x;  // 512 = 4 m * 2 b * 64 fstrips
  int m_ = blk >> 7;
  int b_ = (blk >> 6) & 1;
  int fs = blk & 63;
  int f0 = fs * 4;
  int w0 = threadIdx.x * 4;
  const float* xb = x + (size_t)b_ * 2097152;
  const float* wp_[3] = {wqc + m_ * 72, wkc + m_ * 72, wvc + m_ * 72};
  float bias_[3] = {bq[m_], bk[m_], bv[m_]};

  float acc[3][4][4];
#pragma unroll
  for (int p = 0; p < 3; ++p)
#pragma unroll
    for (int fi = 0; fi < 4; ++fi)
#pragma unroll
      for (int j = 0; j < 4; ++j) acc[p][fi][j] = bias_[p];

  for (int c = 0; c < 8; ++c) {
    const float* xc = xb + c * 262144;
    float w9[3][9];
#pragma unroll
    for (int p = 0; p < 3; ++p)
#pragma unroll
      for (int t = 0; t < 9; ++t) w9[p][t] = wp_[p][c * 9 + t];
    float rows[6][6];
#pragma unroll
    for (int ri = 0; ri < 6; ++ri) loadrow(rows[ri], xc, f0 - 1 + ri, w0);
#pragma unroll
    for (int fi = 0; fi < 4; ++fi) {
#pragma unroll
      for (int p = 0; p < 3; ++p) {
#pragma unroll
        for (int j = 0; j < 4; ++j) {
          float s = acc[p][fi][j];
          s += rows[fi][j] * w9[p][0] + rows[fi][j + 1] * w9[p][1] + rows[fi][j + 2] * w9[p][2];
          s += rows[fi + 1][j] * w9[p][3] + rows[fi + 1][j + 1] * w9[p][4] + rows[fi + 1][j + 2] * w9[p][5];
          s += rows[fi + 2][j] * w9[p][6] + rows[fi + 2][j + 1] * w9[p][7] + rows[fi + 2][j + 2] * w9[p][8];
          acc[p][fi][j] = s;
        }
      }
    }
  }
#pragma unroll
  for (int p = 0; p < 3; ++p) {
    int mat = p * 8 + b_ * 4 + m_;
    short* yp = y + (size_t)mat * 262144;
#pragma unroll
    for (int fi = 0; fi < 4; ++fi) {
      uint2 pk;
      pk.x = pack2(acc[p][fi][0], acc[p][fi][1]);
      pk.y = pack2(acc[p][fi][2], acc[p][fi][3]);
      *(uint2*)(yp + (f0 + fi) * 1024 + w0) = pk;
    }
  }
}

// ---------------------------------------------------------------------------
// K3: per-map linear (MFMA GEMM) + RoPE, with FUSED y-transpose.
// ---------------------------------------------------------------------------
__global__ __launch_bounds__(256) void k_qkv(const short* wlin, const short* y,
                                             const float* ct, const float* st,
                                             short* qws, short* kws, short* vws) {
  __shared__ short ytile[64][264];
  int blk = blockIdx.x;  // 24 pbm * 16 wtiles
  int pbm = blk >> 4, wt = blk & 15;
  int p = pbm >> 3, bm = pbm & 7;
  int m_ = bm & 3;
  int tid = threadIdx.x, wv = tid >> 6, l = tid & 63, lr = l & 15, lg = l >> 4;
  const short* wl = wlin + (p * 4 + m_) * 65536;
  const short* yp = y + (size_t)pbm * 262144;
  int w0 = wt * 64;
  int G0 = wv * 64;

  // ---- stage + transpose: wave wv covers f rows [wv*64, wv*64+64) ----
  {
    int h2 = l >> 5, lih = l & 31;
#pragma unroll
    for (int i = 0; i < 32; ++i) {
      int f = wv * 64 + i * 2 + h2;
      unsigned u = *(const unsigned*)(yp + f * 1024 + w0 + lih * 2);
      ytile[lih * 2][f] = (short)(u & 0xffffu);
      ytile[lih * 2 + 1][f] = (short)(u >> 16);
    }
  }
  __syncthreads();

  f32x4 acc[4][4];
#pragma unroll
  for (int i = 0; i < 4; ++i)
#pragma unroll
    for (int j = 0; j < 4; ++j) acc[i][j] = (f32x4){0.f, 0.f, 0.f, 0.f};

  if (p < 2) {
    for (int kc = 0; kc < 256; kc += 32) {
      s16x8 A[4], Bf[4];
#pragma unroll
      for (int gs = 0; gs < 4; ++gs)
        A[gs] = *(const s16x8*)(wl + (G0 + gs * 16 + lr) * 256 + kc + lg * 8);
#pragma unroll
      for (int s = 0; s < 4; ++s)
        Bf[s] = *(const s16x8*)(&ytile[s * 16 + lr][kc + lg * 8]);
#pragma unroll
      for (int gs = 0; gs < 4; ++gs)
#pragma unroll
        for (int s = 0; s < 4; ++s) acc[gs][s] = MFMA16(A[gs], Bf[s], acc[gs][s]);
    }
    short* dst = (p == 0) ? qws : kws;
    float scale = (p == 0) ? 0.0625f : 1.0f;  // fold 1/sqrt(256) into Q
#pragma unroll
    for (int gs = 0; gs < 4; ++gs) {
      int g0v = G0 + gs * 16 + lg * 4;
      int h = g0v >> 5, d0 = g0v & 31;
      int i0 = d0 >> 1;
#pragma unroll
      for (int s = 0; s < 4; ++s) {
        int w = w0 + s * 16 + lr;
        float c0 = ct[w * 16 + i0], sn0 = st[w * 16 + i0];
        float c1 = ct[w * 16 + i0 + 1], sn1 = st[w * 16 + i0 + 1];
        f32x4 v = acc[gs][s];
        float e0 = (v[0] * c0 - v[1] * sn0) * scale;
        float e1 = (v[1] * c0 + v[0] * sn0) * scale;
        float e2 = (v[2] * c1 - v[3] * sn1) * scale;
        float e3 = (v[3] * c1 + v[2] * sn1) * scale;
        uint2 pk;
        pk.x = pack2(e0, e1);
        pk.y = pack2(e2, e3);
        *(uint2*)(dst + (((size_t)bm * 8 + h) * 1024 + w) * 32 + d0) = pk;
      }
    }
  } else {
    for (int kc = 0; kc < 256; kc += 32) {
      s16x8 A[4], Bf[4];
#pragma unroll
      for (int s = 0; s < 4; ++s)
        A[s] = *(const s16x8*)(&ytile[s * 16 + lr][kc + lg * 8]);
#pragma unroll
      for (int gs = 0; gs < 4; ++gs)
        Bf[gs] = *(const s16x8*)(wl + (G0 + gs * 16 + lr) * 256 + kc + lg * 8);
#pragma unroll
      for (int s = 0; s < 4; ++s)
#pragma unroll
        for (int gs = 0; gs < 4; ++gs) acc[s][gs] = MFMA16(A[s], Bf[gs], acc[s][gs]);
    }
#pragma unroll
    for (int s = 0; s < 4; ++s) {
      int wb = w0 + s * 16 + lg * 4;
#pragma unroll
      for (int gs = 0; gs < 4; ++gs) {
        int g = G0 + gs * 16 + lr;
        f32x4 v = acc[s][gs];
        uint2 pk;
        pk.x = pack2(v[0], v[1]);
        pk.y = pack2(v[2], v[3]);
        *(uint2*)(vws + ((size_t)bm * 256 + g) * 1024 + wb) = pk;
      }
    }
  }
}

// ---------------------------------------------------------------------------
// K4: fused attention (R9 structure; prev prefetch deepened 2 -> 4 windows —
// the ONLY change vs the 220.6us R13 build.  In-flight/wave 8KB -> 16KB;
// VGPR +32 is free, occupancy is LDS-capped at 1 block/CU).
// ---------------------------------------------------------------------------
__global__ __launch_bounds__(256, 1) void k_attn(const short* qws, const short* kws,
                                                 const short* vws, const float* prev,
                                                 float* qko, short* aT) {
  __shared__ char smem[155648];
  // LDS: K [0,64K): row k(1024) x 64B, xor ((k&3)<<4)
  //      V [64K,128K): row g(32) x 2048B, xor ((g&7)<<4)
  //      S [128K + wv*4K): 16 q x 256B, xor ((q&7)<<4)
  //      P [144K + wv*2K): 16 q x 128B, xor ((q&7)<<4)
  int blk = blockIdx.x;  // 1024 = 64 bmh * 16 qg
  int bmh = blk >> 4;
  int qg = blk & 15;
  int h = bmh & 7, bm = bmh >> 3;
  int tid = threadIdx.x;
  int wv = tid >> 6, l = tid & 63, lr = l & 15, lg = l >> 4;
  const short* kp = kws + (size_t)bmh * 32768;
  const short* vp = vws + ((size_t)bm * 256 + h * 32) * 1024;

  // ---- stage K (64KB): 16 iters, 64 rows x 64B each (256 thr x 16B) ----
  {
    int row4 = tid >> 2, c = tid & 3;
#pragma unroll
    for (int i = 0; i < 16; ++i) {
      int row = i * 64 + row4;
      s16x8 kv = *(const s16x8*)(kp + row * 32 + c * 8);
      *(s16x8*)(smem + row * 64 + ((c * 16) ^ ((row & 3) << 4))) = kv;
    }
    // ---- stage V (64KB): 16 iters, 2 rows x 2048B each ----
    int g2 = tid >> 7, cb = (tid & 127) * 16;
#pragma unroll
    for (int i = 0; i < 16; ++i) {
      int g = i * 2 + g2;
      s16x8 vv = *(const s16x8*)(vp + g * 1024 + (cb >> 1));
      *(s16x8*)(smem + 65536 + g * 2048 + (cb ^ ((g & 7) << 4))) = vv;
    }
  }
  __syncthreads();

  int q0 = qg * 64 + wv * 16;
  const short* qp = qws + (size_t)bmh * 32768;
  s16x8 qf = *(const s16x8*)(qp + (q0 + lr) * 32 + lg * 8);
  char* Sb = smem + 131072 + wv * 4096;
  char* Pb = smem + 147456 + wv * 2048;
  const float* pvb = prev + (size_t)bmh * 1048576 + (size_t)q0 * 1024;
  float* qob = qko + (size_t)bmh * 1048576 + (size_t)q0 * 1024;
  int pcol = (l & 15) * 4;   // float col within window
  int pcolb = pcol * 4;      // byte col within S row
  f32x4 o0 = {0.f, 0.f, 0.f, 0.f}, o1 = {0.f, 0.f, 0.f, 0.f};
  f32x4 rs = {0.f, 0.f, 0.f, 0.f};  // rs[j]: rowsum partial for q-row j*4+lg
  const f32x4 z4 = {0.f, 0.f, 0.f, 0.f};

  // window body: consume pr (window w), refill pr with window w+4
  auto attn_win = [&](int w, f32x4(&pr)[4]) {
    int k0 = w * 64;
    // QK^T from LDS K
#pragma unroll
    for (int s = 0; s < 4; ++s) {
      int krow = k0 + s * 16 + lr;
      s16x8 kf = *(const s16x8*)(smem + krow * 64 + ((lg * 16) ^ ((krow & 3) << 4)));
      f32x4 sx = MFMA16(kf, qf, z4);  // lane: q=lr(col), k=k0+s*16+lg*4+reg
      *(f32x4*)(Sb + lr * 256 + ((s * 64 + lg * 16) ^ ((lr & 7) << 4))) = sx;
    }
    // row-IO: instr j covers q-rows j*4..j*4+3 (lane: row j*4+lg, 16B of cols)
#pragma unroll
    for (int j = 0; j < 4; ++j) {
      int qr = j * 4 + lg;
      f32x4 sv = *(const f32x4*)(Sb + qr * 256 + (pcolb ^ ((qr & 7) << 4)));
      f32x4 v = sv + pr[j];
      *(f32x4*)(qob + (size_t)qr * 1024 + k0 + pcol) = v;
      float e0 = __expf(v[0]), e1 = __expf(v[1]);
      float e2 = __expf(v[2]), e3 = __expf(v[3]);
      rs[j] += (e0 + e1) + (e2 + e3);
      uint2 pk;
      pk.x = pack2(e0, e1);
      pk.y = pack2(e2, e3);
      *(uint2*)(Pb + qr * 128 + (((l & 15) * 8) ^ ((qr & 7) << 4))) = pk;
    }
    // refill prefetch (4 windows ahead)
    if (w + 4 < 16) {
#pragma unroll
      for (int j = 0; j < 4; ++j)
        pr[j] = *(const f32x4*)(pvb + (size_t)(j * 4 + lg) * 1024 + (w + 4) * 64 + pcol);
    }
    // PV from LDS V
#pragma unroll
    for (int kc = 0; kc < 2; ++kc) {
      s16x8 pa = *(const s16x8*)(Pb + lr * 128 + ((kc * 64 + lg * 16) ^ ((lr & 7) << 4)));
      int kcb = (k0 + kc * 32 + lg * 8) * 2;
      s16x8 vf0 = *(const s16x8*)(smem + 65536 + lr * 2048 + (kcb ^ ((lr & 7) << 4)));
      o0 = MFMA16(pa, vf0, o0);
      s16x8 vf1 = *(const s16x8*)(smem + 65536 + (16 + lr) * 2048 + (kcb ^ ((lr & 7) << 4)));
      o1 = MFMA16(pa, vf1, o1);
    }
  };

  f32x4 pA[4], pB[4], pC[4], pD[4];
#pragma unroll
  for (int j = 0; j < 4; ++j)
    pA[j] = *(const f32x4*)(pvb + (size_t)(j * 4 + lg) * 1024 + 0 + pcol);
#pragma unroll
  for (int j = 0; j < 4; ++j)
    pB[j] = *(const f32x4*)(pvb + (size_t)(j * 4 + lg) * 1024 + 64 + pcol);
#pragma unroll
  for (int j = 0; j < 4; ++j)
    pC[j] = *(const f32x4*)(pvb + (size_t)(j * 4 + lg) * 1024 + 128 + pcol);
#pragma unroll
  for (int j = 0; j < 4; ++j)
    pD[j] = *(const f32x4*)(pvb + (size_t)(j * 4 + lg) * 1024 + 192 + pcol);

  for (int w = 0; w < 16; w += 4) {
    attn_win(w, pA);
    attn_win(w + 1, pB);
    attn_win(w + 2, pC);
    attn_win(w + 3, pD);
  }

  // rowsum reduce across the 16 lanes sharing lg
#pragma unroll
  for (int j = 0; j < 4; ++j) {
    float s = rs[j];
    s += __shfl_xor(s, 1);
    s += __shfl_xor(s, 2);
    s += __shfl_xor(s, 4);
    s += __shfl_xor(s, 8);
    rs[j] = s;
  }
  // route rowsums to PV-frag layout via wave-private S scratch
  if (lr == 0) {
#pragma unroll
    for (int j = 0; j < 4; ++j) *(float*)(Sb + (j * 4 + lg) * 4) = rs[j];
  }
  f32x4 sums = *(const f32x4*)(Sb + lg * 16);
  f32x4 inv = {1.f / sums[0], 1.f / sums[1], 1.f / sums[2], 1.f / sums[3]};
  o0 *= inv;
  o1 *= inv;
  short* ap = aT + (size_t)bm * 262144;
#pragma unroll
  for (int r = 0; r < 4; ++r) {
    int row = q0 + lg * 4 + r;
    ap[row * 256 + h * 32 + lr] = f2bf(o0[r]);
    ap[row * 256 + h * 32 + 16 + lr] = f2bf(o1[r]);
  }
}

// ---------------------------------------------------------------------------
// K5: z projection with FUSED x-transpose.
// ---------------------------------------------------------------------------
__global__ __launch_bounds__(256) void k_zproj(const short* wopw, const float* x,
                                               const short* aT, short* z) {
  __shared__ short xtile[64][264];
  int blk = blockIdx.x;  // 24 bc * 16 wtiles
  int bc = blk >> 4, wt = blk & 15;
  int b_ = bc / 12, c_ = bc % 12;
  const short* wl = wopw + c_ * 65536;
  int tid = threadIdx.x, wv = tid >> 6, l = tid & 63, lr = l & 15, lg = l >> 4;
  int w0 = wt * 64, G0 = wv * 64;
  bool use_lds = (c_ < 8);
  const short* asrc = aT + ((size_t)b_ * 4 + (c_ - 8)) * 262144;

  if (use_lds) {
    const float* xp = x + ((size_t)b_ * 8 + c_) * 262144;
    int h2 = l >> 5, lih = l & 31;
#pragma unroll
    for (int i = 0; i < 32; ++i) {
      int f = wv * 64 + i * 2 + h2;
      uint2 u = *(const uint2*)(xp + f * 1024 + w0 + lih * 2);
      xtile[lih * 2][f] = f2bf(__builtin_bit_cast(float, u.x));
      xtile[lih * 2 + 1][f] = f2bf(__builtin_bit_cast(float, u.y));
    }
  }
  __syncthreads();

  f32x4 acc[4][4];
#pragma unroll
  for (int i = 0; i < 4; ++i)
#pragma unroll
    for (int j = 0; j < 4; ++j) acc[i][j] = (f32x4){0.f, 0.f, 0.f, 0.f};
  for (int kc = 0; kc < 256; kc += 32) {
    s16x8 A[4], Bf[4];
#pragma unroll
    for (int s = 0; s < 4; ++s)
      A[s] = use_lds ? *(const s16x8*)(&xtile[s * 16 + lr][kc + lg * 8])
                     : *(const s16x8*)(asrc + (w0 + s * 16 + lr) * 256 + kc + lg * 8);
#pragma unroll
    for (int gs = 0; gs < 4; ++gs)
      Bf[gs] = *(const s16x8*)(wl + (G0 + gs * 16 + lr) * 256 + kc + lg * 8);
#pragma unroll
    for (int s = 0; s < 4; ++s)
#pragma unroll
      for (int gs = 0; gs < 4; ++gs) acc[s][gs] = MFMA16(A[s], Bf[gs], acc[s][gs]);
  }
  short* zp = z + (size_t)bc * 262144;
#pragma unroll
  for (int s = 0; s < 4; ++s) {
    int wb = w0 + s * 16 + lg * 4;
#pragma unroll
    for (int gs = 0; gs < 4; ++gs) {
      int g = G0 + gs * 16 + lr;
      f32x4 v = acc[s][gs];
      uint2 pk;
      pk.x = pack2(v[0], v[1]);
      pk.y = pack2(v[2], v[3]);
      *(uint2*)(zp + g * 1024 + wb) = pk;
    }
  }
}

// ---------------------------------------------------------------------------
// K6: out[b][o][g][w] = sum_c wo_dw[o][c] * z[b][c][g][w]
// ---------------------------------------------------------------------------
__global__ __launch_bounds__(256) void k_dw(const short* z, const float* dw, float* out0) {
  __shared__ float wdw[96];
  if (threadIdx.x < 96) wdw[threadIdx.x] = dw[threadIdx.x];
  __syncthreads();
  int id = blockIdx.x * 256 + threadIdx.x;  // 131072 threads, 4 w each
  int w4 = id & 255, g = (id >> 8) & 255, b_ = id >> 16;
  const short* zb = z + ((size_t)b_ * 12) * 262144 + g * 1024 + w4 * 4;
  float zv[12][4];
#pragma unroll
  for (int c = 0; c < 12; ++c) {
    uint2 u = *(const uint2*)(zb + (size_t)c * 262144);
    zv[c][0] = bf2f(u.x & 0xffffu);
    zv[c][1] = bf2f(u.x >> 16);
    zv[c][2] = bf2f(u.y & 0xffffu);
    zv[c][3] = bf2f(u.y >> 16);
  }
  float* ob = out0 + ((size_t)b_ * 8) * 262144 + g * 1024 + w4 * 4;
#pragma unroll
  for (int o = 0; o < 8; ++o) {
    f32x4 s = {0.f, 0.f, 0.f, 0.f};
#pragma unroll
    for (int c = 0; c < 12; ++c) {
      float wc = wdw[o * 12 + c];
      s[0] += wc * zv[c][0];
      s[1] += wc * zv[c][1];
      s[2] += wc * zv[c][2];
      s[3] += wc * zv[c][3];
    }
    *(f32x4*)(ob + (size_t)o * 262144) = s;
  }
}

// ---------------------------------------------------------------------------
extern "C" void kernel_launch(void* const* d_in, const int* in_sizes, int n_in,
                              void* d_out, int out_size, void* d_ws, size_t ws_size,
                              hipStream_t stream) {
  const float* x = (const float*)d_in[0];
  const float* prevqk = (const float*)d_in[1];
  const float* wq_conv = (const float*)d_in[2];
  const float* bq = (const float*)d_in[3];
  const float* wq_lin = (const float*)d_in[4];
  const float* wk_conv = (const float*)d_in[5];
  const float* bk = (const float*)d_in[6];
  const float* wk_lin = (const float*)d_in[7];
  const float* wv_conv = (const float*)d_in[8];
  const float* bv = (const float*)d_in[9];
  const float* wv_lin = (const float*)d_in[10];
  const float* wo_pw = (const float*)d_in[11];
  const float* wo_dw = (const float*)d_in[12];

  float* out0 = (float*)d_out;
  float* qkout = out0 + 4194304;  // out[2,8,256,1024] then qk[2,4,8,1024,1024]

  char* ws = (char*)d_ws;
  short* wlin_b = (short*)ws;               // 786432 bf16
  short* wopw_b = wlin_b + 786432;          // 786432 bf16
  float* ct = (float*)(ws + 3145728);       // 16384 f32
  float* st = ct + 16384;                   // 16384 f32
  short* y_b = (short*)(ws + 3276800);      // 6291456 bf16   y[p][b][m][f][w]
  short* q_b = y_b + 6291456;               // 2097152 bf16   q[b][m][h][w][d] (scaled 1/16)
  short* k_b = q_b + 2097152;               // 2097152 bf16
  short* v_b = k_b + 2097152;               // 2097152 bf16   v[b][m][g][w]
  short* aT_b = v_b + 2097152;              // 2097152 bf16   aT[b][m][w][f]
  short* z_b = (short*)(ws + 53608448);     // 6291456 bf16   z[b][c12][g][w]

  k_prep<<<3072, 256, 0, stream>>>(wq_lin, wk_lin, wv_lin, wo_pw, wlin_b, wopw_b, ct, st);
  k_conv<<<512, 256, 0, stream>>>(x, wq_conv, bq, wk_conv, bk, wv_conv, bv, y_b);
  k_qkv<<<384, 256, 0, stream>>>(wlin_b, y_b, ct, st, q_b, k_b, v_b);
  k_attn<<<1024, 256, 0, stream>>>(q_b, k_b, v_b, prevqk, qkout, aT_b);
  k_zproj<<<384, 256, 0, stream>>>(wopw_b, x, aT_b, z_b);
  k_dw<<<512, 256, 0, stream>>>(z_b, wo_dw, out0);
}